// Round 2
// baseline (157.676 us; speedup 1.0000x reference)
//
#include <hip/hip_runtime.h>
#include <hip/hip_bf16.h>
#include <stdint.h>

typedef __attribute__((ext_vector_type(8))) short bf16x8;
typedef __attribute__((ext_vector_type(4))) short bf16x4;
typedef __attribute__((ext_vector_type(4))) float f32x4;
typedef __attribute__((ext_vector_type(4))) unsigned short us4;

#define MFMA32(a, b, c) __builtin_amdgcn_mfma_f32_16x16x32_bf16(a, b, c, 0, 0, 0)

#if defined(__has_builtin) && __has_builtin(__builtin_amdgcn_mfma_f32_16x16x16bf16_1k)
__device__ __forceinline__ f32x4 MFMA16(bf16x4 a, bf16x4 b, f32x4 c) {
    return __builtin_amdgcn_mfma_f32_16x16x16bf16_1k(a, b, c, 0, 0, 0);
}
#elif defined(__has_builtin) && __has_builtin(__builtin_amdgcn_mfma_f32_16x16x16_bf16)
__device__ __forceinline__ f32x4 MFMA16(bf16x4 a, bf16x4 b, f32x4 c) {
    return __builtin_amdgcn_mfma_f32_16x16x16_bf16(a, b, c, 0, 0, 0);
}
#else
__device__ __forceinline__ f32x4 MFMA16(bf16x4 a, bf16x4 b, f32x4 c) {
    f32x4 d;
    asm volatile("v_mfma_f32_16x16x16_bf16 %0, %1, %2, %3\n\ts_nop 7\n\ts_nop 2"
                 : "=v"(d) : "v"(a), "v"(b), "v"(c));
    return d;
}
#endif

__device__ __forceinline__ short f2bf(float f) {
    union { float f; uint32_t u; } v; v.f = f;
    uint32_t u = v.u;
    u = (u + 0x7FFFu + ((u >> 16) & 1u)) >> 16;  // RNE
    return (short)u;
}

__device__ __forceinline__ uint32_t cvt_pk_bf16(float lo, float hi) {
    uint32_t r;
    asm("v_cvt_pk_bf16_f32 %0, %1, %2" : "=v"(r) : "v"(lo), "v"(hi));
    return r;
}

// ---------------------------------------------------------------------------
// Kernel 1: WT_bf16[192][1024]; cols 0-63 = Wq * 0.125*log2e (exp2-domain
// softmax), 64-127 = Wk, 128-191 = Wv. biasC[192] likewise.
// ---------------------------------------------------------------------------
#define QSCALE 0.18033688011112042f   // 0.125 * log2(e)

__global__ void wt_prep(const float* __restrict__ Wk, const float* __restrict__ bk,
                        const float* __restrict__ Wq, const float* __restrict__ bq,
                        const float* __restrict__ Wv, const float* __restrict__ bv,
                        short* __restrict__ WT, float* __restrict__ biasC) {
    int i = blockIdx.x * 256 + threadIdx.x;
    if (i < 192 * 1024) {
        int c = i >> 10, k = i & 1023, cc = c & 63;
        const float* W; float sc;
        if (c < 64)       { W = Wq; sc = QSCALE; }
        else if (c < 128) { W = Wk; sc = 1.0f;   }
        else              { W = Wv; sc = 1.0f;   }
        WT[i] = f2bf(W[k * 64 + cc] * sc);
    }
    if (blockIdx.x == 0 && threadIdx.x < 192) {
        int c = threadIdx.x;
        float bb;
        if (c < 64)       bb = bq[c] * QSCALE;
        else if (c < 128) bb = bk[c - 64];
        else              bb = bv[c - 128];
        biasC[c] = bb;
    }
}

// ---------------------------------------------------------------------------
// Kernel 2: QKV projection. 1024 blocks x 256 thr. Block = 16 rows; the 4
// waves split K (256 each) and merge partials through LDS. X read once.
// ---------------------------------------------------------------------------
__global__ __launch_bounds__(256, 4) void qkv_proj(
        const float* __restrict__ X, const short* __restrict__ WT,
        const float* __restrict__ biasC,
        short* __restrict__ Qb, short* __restrict__ Kb, short* __restrict__ Vt) {
    const int lane = threadIdx.x & 63, w = threadIdx.x >> 6;
    const int l15 = lane & 15, h = lane >> 4;
    const int row0 = blockIdx.x * 16;
    const int k0 = w * 256 + h * 8;

    f32x4 acc[12];
#pragma unroll
    for (int t = 0; t < 12; t++) acc[t] = (f32x4){0.f, 0.f, 0.f, 0.f};

    const float* xb = X + (size_t)(row0 + l15) * 1024 + k0;
    const short* wb = WT + (size_t)l15 * 1024 + k0;

    for (int kc = 0; kc < 256; kc += 32) {
        const float4 a0 = *(const float4*)(xb + kc);
        const float4 a1 = *(const float4*)(xb + kc + 4);
        bf16x8 af;
        af[0] = f2bf(a0.x); af[1] = f2bf(a0.y); af[2] = f2bf(a0.z); af[3] = f2bf(a0.w);
        af[4] = f2bf(a1.x); af[5] = f2bf(a1.y); af[6] = f2bf(a1.z); af[7] = f2bf(a1.w);
#pragma unroll
        for (int ct = 0; ct < 12; ct++) {
            bf16x8 bf = *(const bf16x8*)(wb + (size_t)ct * 16 * 1024 + kc);
            acc[ct] = MFMA32(af, bf, acc[ct]);
        }
    }

    __shared__ float buf[4][12][16][17];   // padded: conflict-free merge
#pragma unroll
    for (int ct = 0; ct < 12; ct++)
#pragma unroll
        for (int r = 0; r < 4; r++)
            buf[w][ct][h * 4 + r][l15] = acc[ct][r];
    __syncthreads();

    const int b = row0 >> 12, srow = row0 & 4095;

    // Q (ct 0-3) and K (ct 4-7)
#pragma unroll
    for (int i = 0; i < 8; i++) {
        const int e = threadIdx.x + 256 * i;
        const int ct = e >> 8, row = (e >> 4) & 15, col = e & 15;
        float val = buf[0][ct][row][col] + buf[1][ct][row][col]
                  + buf[2][ct][row][col] + buf[3][ct][row][col]
                  + biasC[ct * 16 + col];
        if (ct < 4) Qb[(size_t)(row0 + row) * 64 + ct * 16 + col] = f2bf(val);
        else        Kb[(size_t)(row0 + row) * 64 + (ct - 4) * 16 + col] = f2bf(val);
    }
    // V -> Vt[b][hd][s] (transposed), packed 4-s stores
    {
        const int ctv = (threadIdx.x >> 4) & 3;         // 0..3 -> ct 8..11
        const int col = threadIdx.x & 15;
        const int rg = threadIdx.x >> 6;                // 0..3
        const int hd = ctv * 16 + col;
        const float bias = biasC[128 + hd];
        us4 pk;
#pragma unroll
        for (int r = 0; r < 4; r++) {
            const int row = rg * 4 + r;
            float val = buf[0][8 + ctv][row][col] + buf[1][8 + ctv][row][col]
                      + buf[2][8 + ctv][row][col] + buf[3][8 + ctv][row][col] + bias;
            pk[r] = (unsigned short)f2bf(val);
        }
        *(us4*)(Vt + ((size_t)(b * 64 + hd)) * 4096 + srow + rg * 4) = pk;
    }
}

// ---------------------------------------------------------------------------
// Kernel 3: causal flash attention, swapped-operand form.
// Block = 32 q-rows (one batch); 4 waves split the KV tiles; each wave holds
// TWO 16-q fragments (shares K/V fragment loads). P stays in registers:
// QK^T uses mfma(K,Q) (16x16x32), PV uses mfma(V^T, P^T) (16x16x16), whose
// B-fragment k-layout (4h+j) equals the QK D-layout (4h+r). Softmax is
// 2 shuffles; exp2-domain (scale folded into Q).
// ---------------------------------------------------------------------------
__device__ __forceinline__ void softmax_update(const f32x4 s[4], float& m, float& l,
                                               f32x4 o[4], bf16x4 pb[4]) {
    float mx = s[0][0];
#pragma unroll
    for (int c = 0; c < 4; c++)
#pragma unroll
        for (int r = 0; r < 4; r++) mx = fmaxf(mx, s[c][r]);
    mx = fmaxf(mx, __shfl_xor(mx, 16));
    mx = fmaxf(mx, __shfl_xor(mx, 32));
    const float mn = fmaxf(m, mx);
    const float fac = exp2f(m - mn);
    m = mn;
    float p[4][4];
    float sum = 0.f;
#pragma unroll
    for (int c = 0; c < 4; c++)
#pragma unroll
        for (int r = 0; r < 4; r++) { p[c][r] = exp2f(s[c][r] - mn); sum += p[c][r]; }
    sum += __shfl_xor(sum, 16);
    sum += __shfl_xor(sum, 32);
    l = l * fac + sum;
#pragma unroll
    for (int c = 0; c < 4; c++) o[c] *= fac;
#pragma unroll
    for (int c = 0; c < 4; c++) {
        union { bf16x4 v; uint32_t u[2]; } pk;
        pk.u[0] = cvt_pk_bf16(p[c][0], p[c][1]);
        pk.u[1] = cvt_pk_bf16(p[c][2], p[c][3]);
        pb[c] = pk.v;
    }
}

__global__ __launch_bounds__(256, 3) void attn(
        const short* __restrict__ Qb, const short* __restrict__ Kb,
        const short* __restrict__ Vt, float* __restrict__ out) {
    const int lane = threadIdx.x & 63, wg = threadIdx.x >> 6;
    const int l15 = lane & 15, h = lane >> 4;
    const int g = blockIdx.x;
    const int b = g >> 7;
    const int i = g & 127;
    const int u = (i & 1) ? (127 - (i >> 1)) : (i >> 1);   // heavy/light interleave
    const int row32 = u * 32;
    const int lt = u >> 1;                                 // last (diagonal) KV tile
    const size_t bbase = (size_t)b * 4096 * 64;

    // Q fragments (B-operand: col = q = l15, k = h*8+j)
    const short* qp0 = Qb + bbase + (size_t)(row32 + l15) * 64 + h * 8;
    const short* qp1 = qp0 + 16 * 64;
    const bf16x8 q00 = *(const bf16x8*)qp0,  q01 = *(const bf16x8*)(qp0 + 32);
    const bf16x8 q10 = *(const bf16x8*)qp1,  q11 = *(const bf16x8*)(qp1 + 32);

    f32x4 o0[4], o1[4];
    float m0 = -__builtin_inff(), m1 = -__builtin_inff(), l0 = 0.f, l1 = 0.f;
#pragma unroll
    for (int t = 0; t < 4; t++) { o0[t] = (f32x4){0,0,0,0}; o1[t] = (f32x4){0,0,0,0}; }

    for (int kt = wg; kt <= lt; kt += 4) {
        const short* kb = Kb + bbase + (size_t)kt * 64 * 64;
        f32x4 s0[4], s1[4];
#pragma unroll
        for (int c = 0; c < 4; c++) {
            const short* kp = kb + (size_t)(c * 16 + l15) * 64 + h * 8;
            const bf16x8 kf0 = *(const bf16x8*)kp;
            const bf16x8 kf1 = *(const bf16x8*)(kp + 32);
            f32x4 z = (f32x4){0,0,0,0};
            z = MFMA32(kf0, q00, z);  s0[c] = MFMA32(kf1, q01, z);
            z = (f32x4){0,0,0,0};
            z = MFMA32(kf0, q10, z);  s1[c] = MFMA32(kf1, q11, z);
        }
        if (kt == lt) {   // diagonal: mask key > q
            const int q0g = row32 + l15, q1g = q0g + 16;
#pragma unroll
            for (int c = 0; c < 4; c++) {
#pragma unroll
                for (int r = 0; r < 4; r++) {
                    const int key = kt * 64 + c * 16 + h * 4 + r;
                    if (key > q0g) s0[c][r] = -1e30f;
                    if (key > q1g) s1[c][r] = -1e30f;
                }
            }
        }
        bf16x4 pb0[4], pb1[4];
        softmax_update(s0, m0, l0, o0, pb0);
        softmax_update(s1, m1, l1, o1, pb1);

        // PV: A = V^T (row=d, k=key), B = P^T in-register
        const short* vb = Vt + (size_t)b * 64 * 4096 + kt * 64;
#pragma unroll
        for (int ct = 0; ct < 4; ct++) {
            const short* vp = vb + (size_t)(ct * 16 + l15) * 4096 + h * 4;
#pragma unroll
            for (int c = 0; c < 4; c++) {
                const bf16x4 vf = *(const bf16x4*)(vp + c * 16);
                o0[ct] = MFMA16(vf, pb0[c], o0[ct]);
                o1[ct] = MFMA16(vf, pb1[c], o1[ct]);
            }
        }
    }

    // ---- merge the 4 split-K wave partials ----
    __shared__ float c_m[4][32], c_l[4][32];
    __shared__ float c_o[4][64][33];      // pad 33: conflict-free writes
    if (h == 0) {
        c_m[wg][l15] = m0;  c_m[wg][16 + l15] = m1;
        c_l[wg][l15] = l0;  c_l[wg][16 + l15] = l1;
    }
#pragma unroll
    for (int ct = 0; ct < 4; ct++)
#pragma unroll
        for (int r = 0; r < 4; r++) {
            c_o[wg][ct * 16 + h * 4 + r][l15]      = o0[ct][r];
            c_o[wg][ct * 16 + h * 4 + r][16 + l15] = o1[ct][r];
        }
    __syncthreads();

#pragma unroll
    for (int it = 0; it < 8; it++) {
        const int e = threadIdx.x + 256 * it;
        const int q = e >> 6, d = e & 63;
        const float M = fmaxf(fmaxf(c_m[0][q], c_m[1][q]), fmaxf(c_m[2][q], c_m[3][q]));
        float L = 0.f, V = 0.f;
#pragma unroll
        for (int ww = 0; ww < 4; ww++) {
            const float ee = exp2f(c_m[ww][q] - M);
            L += ee * c_l[ww][q];
            V += ee * c_o[ww][d][q];
        }
        out[bbase + (size_t)(row32 + q) * 64 + d] = V / L;
    }
}

// ---------------------------------------------------------------------------
extern "C" void kernel_launch(void* const* d_in, const int* in_sizes, int n_in,
                              void* d_out, int out_size, void* d_ws, size_t ws_size,
                              hipStream_t stream) {
    const float* x  = (const float*)d_in[0];
    // d_in[1] = causal mask (structure known, not read)
    const float* Wk = (const float*)d_in[2];
    const float* bk = (const float*)d_in[3];
    const float* Wq = (const float*)d_in[4];
    const float* bq = (const float*)d_in[5];
    const float* Wv = (const float*)d_in[6];
    const float* bv = (const float*)d_in[7];
    float* out = (float*)d_out;

    char* ws = (char*)d_ws;
    short* WT    = (short*)(ws);                          // 384 KB
    float* biasC = (float*)(ws + 393216);                 // 768 B
    short* Qb    = (short*)(ws + (size_t)1 * (1 << 20));  // 2 MB (exp2-scaled)
    short* Kb    = (short*)(ws + (size_t)3 * (1 << 20));  // 2 MB
    short* Vt    = (short*)(ws + (size_t)5 * (1 << 20));  // 2 MB, [b][hd][s]

    wt_prep<<<768, 256, 0, stream>>>(Wk, bk, Wq, bq, Wv, bv, WT, biasC);
    qkv_proj<<<1024, 256, 0, stream>>>(x, WT, biasC, Qb, Kb, Vt);
    attn<<<512, 256, 0, stream>>>(Qb, Kb, Vt, out);
}

// Round 4
// 134.963 us; speedup vs baseline: 1.1683x; 1.1683x over previous
//
#include <hip/hip_runtime.h>
#include <hip/hip_bf16.h>
#include <stdint.h>

typedef __attribute__((ext_vector_type(8))) short bf16x8;
typedef __attribute__((ext_vector_type(4))) short bf16x4;
typedef __attribute__((ext_vector_type(4))) float f32x4;
typedef __attribute__((ext_vector_type(4))) unsigned short us4;

#define MFMA32(a, b, c) __builtin_amdgcn_mfma_f32_16x16x32_bf16(a, b, c, 0, 0, 0)

#if defined(__has_builtin) && __has_builtin(__builtin_amdgcn_mfma_f32_16x16x16bf16_1k)
__device__ __forceinline__ f32x4 MFMA16(bf16x4 a, bf16x4 b, f32x4 c) {
    return __builtin_amdgcn_mfma_f32_16x16x16bf16_1k(a, b, c, 0, 0, 0);
}
#elif defined(__has_builtin) && __has_builtin(__builtin_amdgcn_mfma_f32_16x16x16_bf16)
__device__ __forceinline__ f32x4 MFMA16(bf16x4 a, bf16x4 b, f32x4 c) {
    return __builtin_amdgcn_mfma_f32_16x16x16_bf16(a, b, c, 0, 0, 0);
}
#else
__device__ __forceinline__ f32x4 MFMA16(bf16x4 a, bf16x4 b, f32x4 c) {
    f32x4 d;
    asm volatile("v_mfma_f32_16x16x16_bf16 %0, %1, %2, %3\n\ts_nop 7\n\ts_nop 2"
                 : "=v"(d) : "v"(a), "v"(b), "v"(c));
    return d;
}
#endif

__device__ __forceinline__ short f2bf(float f) {
    union { float f; uint32_t u; } v; v.f = f;
    uint32_t u = v.u;
    u = (u + 0x7FFFu + ((u >> 16) & 1u)) >> 16;  // RNE
    return (short)u;
}
__device__ __forceinline__ float bf2f(short s) {
    union { uint32_t u; float f; } v; v.u = ((uint32_t)(unsigned short)s) << 16;
    return v.f;
}
__device__ __forceinline__ uint32_t cvt_pk_bf16(float lo, float hi) {
    uint32_t r;
    asm("v_cvt_pk_bf16_f32 %0, %1, %2" : "=v"(r) : "v"(lo), "v"(hi));
    return r;
}

#define QSCALE 0.18033688011112042f   // 0.125 * log2(e)

// ---------------------------------------------------------------------------
// Kernel 1: WT_bf16[192][1024] (rows 0-63 Wq*QSCALE | 64-127 Wk | 128-191 Wv)
// ---------------------------------------------------------------------------
__global__ void wt_prep(const float* __restrict__ Wk, const float* __restrict__ bk,
                        const float* __restrict__ Wq, const float* __restrict__ bq,
                        const float* __restrict__ Wv, const float* __restrict__ bv,
                        short* __restrict__ WT, float* __restrict__ biasC) {
    int i = blockIdx.x * 256 + threadIdx.x;
    if (i < 192 * 1024) {
        int c = i >> 10, k = i & 1023, cc = c & 63;
        const float* W; float sc;
        if (c < 64)       { W = Wq; sc = QSCALE; }
        else if (c < 128) { W = Wk; sc = 1.0f;   }
        else              { W = Wv; sc = 1.0f;   }
        WT[i] = f2bf(W[k * 64 + cc] * sc);
    }
    if (blockIdx.x == 0 && threadIdx.x < 192) {
        int c = threadIdx.x;
        float bb;
        if (c < 64)       bb = bq[c] * QSCALE;
        else if (c < 128) bb = bk[c - 64];
        else              bb = bv[c - 128];
        biasC[c] = bb;
    }
}

// ---------------------------------------------------------------------------
// Kernel 2: QKV projection, X staged through LDS (coalesced).
// 1024 blocks x 256 thr; block = 16 rows; 4 waves split K (256 each).
// ---------------------------------------------------------------------------
__global__ __launch_bounds__(256) void qkv_proj(
        const float* __restrict__ X, const short* __restrict__ WT,
        const float* __restrict__ biasC,
        short* __restrict__ Qb, short* __restrict__ Kb, short* __restrict__ Vt) {
    union SM {
        short stage[16][1032];        // 33 KB, pad 8 -> conflict-free frags
        float merge[12][16][4][17];   // 52 KB
    };
    __shared__ SM sm;
    const int t = threadIdx.x;
    const int lane = t & 63, w = t >> 6, l15 = lane & 15, h = lane >> 4;
    const int row0 = blockIdx.x * 16;

    // ---- stage X tile (16 x 1024) as bf16; 512B-contiguous global reads ----
    {
        const int srow = t >> 4, sl = t & 15;
        const float* xr = X + (size_t)(row0 + srow) * 1024 + sl * 8;
        short* dr = &sm.stage[srow][sl * 8];
#pragma unroll
        for (int it = 0; it < 8; it++) {
            const float4 a0 = *(const float4*)(xr + it * 128);
            const float4 a1 = *(const float4*)(xr + it * 128 + 4);
            uint4 pk;
            pk.x = cvt_pk_bf16(a0.x, a0.y);
            pk.y = cvt_pk_bf16(a0.z, a0.w);
            pk.z = cvt_pk_bf16(a1.x, a1.y);
            pk.w = cvt_pk_bf16(a1.z, a1.w);
            *(uint4*)(dr + it * 128) = pk;   // FIX: 128 bf16 per it (was 256)
        }
    }
    __syncthreads();

    f32x4 acc[12];
#pragma unroll
    for (int ct = 0; ct < 12; ct++) acc[ct] = (f32x4){0.f, 0.f, 0.f, 0.f};

    const short* ar = &sm.stage[l15][w * 256 + h * 8];
    const short* wb = WT + (size_t)l15 * 1024 + w * 256 + h * 8;

    for (int kc = 0; kc < 256; kc += 32) {
        const bf16x8 af = *(const bf16x8*)(ar + kc);
#pragma unroll
        for (int ct = 0; ct < 12; ct++) {
            const bf16x8 bf = *(const bf16x8*)(wb + (size_t)ct * 16 * 1024 + kc);
            acc[ct] = MFMA32(af, bf, acc[ct]);
        }
    }
    __syncthreads();   // stage dead, reuse as merge buffer

#pragma unroll
    for (int ct = 0; ct < 12; ct++)
#pragma unroll
        for (int r = 0; r < 4; r++)
            sm.merge[ct][h * 4 + r][w][l15] = acc[ct][r];
    __syncthreads();

    const int b = row0 >> 12, srow = row0 & 4095;

    // Q (ct 0-3) and K (ct 4-7)
#pragma unroll
    for (int i = 0; i < 8; i++) {
        const int e = t + 256 * i;
        const int ct = e >> 8, row = (e >> 4) & 15, col = e & 15;
        float val = sm.merge[ct][row][0][col] + sm.merge[ct][row][1][col]
                  + sm.merge[ct][row][2][col] + sm.merge[ct][row][3][col]
                  + biasC[ct * 16 + col];
        if (ct < 4) Qb[(size_t)(row0 + row) * 64 + ct * 16 + col] = f2bf(val);
        else        Kb[(size_t)(row0 + row) * 64 + (ct - 4) * 16 + col] = f2bf(val);
    }
    // V -> Vt[b][hd][s] (transposed), packed 4-s stores
    {
        const int ctv = (t >> 4) & 3;
        const int col = t & 15;
        const int rg = t >> 6;
        const int hd = ctv * 16 + col;
        const float bias = biasC[128 + hd];
        us4 pk;
#pragma unroll
        for (int r = 0; r < 4; r++) {
            const int row = rg * 4 + r;
            float val = sm.merge[8 + ctv][row][0][col] + sm.merge[8 + ctv][row][1][col]
                      + sm.merge[8 + ctv][row][2][col] + sm.merge[8 + ctv][row][3][col] + bias;
            pk[r] = (unsigned short)f2bf(val);
        }
        *(us4*)(Vt + ((size_t)(b * 64 + hd)) * 4096 + srow + rg * 4) = pk;
    }
}

// ---------------------------------------------------------------------------
// Kernel 3: causal flash attention, chunked split-K across blocks.
// Task j = (b, qtile u of 32 rows, chunk c of 1024 keys); 320 tasks/batch.
// 4 waves split the chunk's <=16 KV tiles; partials (m,l,O-bf16) -> ws.
// ---------------------------------------------------------------------------
__device__ __forceinline__ void softmax_update(const f32x4 s[4], float& m, float& l,
                                               f32x4 o[4], bf16x4 pb[4]) {
    float mx = s[0][0];
#pragma unroll
    for (int c = 0; c < 4; c++)
#pragma unroll
        for (int r = 0; r < 4; r++) mx = fmaxf(mx, s[c][r]);
    mx = fmaxf(mx, __shfl_xor(mx, 16));
    mx = fmaxf(mx, __shfl_xor(mx, 32));
    const float mn = fmaxf(m, mx);
    const float fac = exp2f(m - mn);
    m = mn;
    float p[4][4];
    float sum = 0.f;
#pragma unroll
    for (int c = 0; c < 4; c++)
#pragma unroll
        for (int r = 0; r < 4; r++) { p[c][r] = exp2f(s[c][r] - mn); sum += p[c][r]; }
    sum += __shfl_xor(sum, 16);
    sum += __shfl_xor(sum, 32);
    l = l * fac + sum;
#pragma unroll
    for (int c = 0; c < 4; c++) o[c] *= fac;
#pragma unroll
    for (int c = 0; c < 4; c++) {
        union { bf16x4 v; uint32_t u[2]; } pk;
        pk.u[0] = cvt_pk_bf16(p[c][0], p[c][1]);
        pk.u[1] = cvt_pk_bf16(p[c][2], p[c][3]);
        pb[c] = pk.v;
    }
}

__global__ __launch_bounds__(256) void attn(
        const short* __restrict__ Qb, const short* __restrict__ Kb,
        const short* __restrict__ Vt,
        short* __restrict__ PO, float* __restrict__ PM, float* __restrict__ PL) {
    const int lane = threadIdx.x & 63, wg = threadIdx.x >> 6;
    const int l15 = lane & 15, h = lane >> 4;
    const int j = blockIdx.x;
    const int b = j / 320, jj = j - b * 320;
    int u, c;
    if (jj < 32)       { u = jj;                 c = 0; }
    else if (jj < 96)  { u = 32 + ((jj - 32) >> 1);  c = (jj - 32) & 1; }
    else if (jj < 192) { const int q3 = (jj - 96) / 3; u = 64 + q3; c = (jj - 96) - 3 * q3; }
    else               { u = 96 + ((jj - 192) >> 2); c = (jj - 192) & 3; }
    const int row32 = u * 32;
    const int lt = u >> 1;                        // diagonal KV tile
    const int tend = min(c * 16 + 15, lt);
    const size_t bbase = (size_t)b * 4096 * 64;

    const short* qp0 = Qb + bbase + (size_t)(row32 + l15) * 64 + h * 8;
    const short* qp1 = qp0 + 16 * 64;
    const bf16x8 q00 = *(const bf16x8*)qp0,  q01 = *(const bf16x8*)(qp0 + 32);
    const bf16x8 q10 = *(const bf16x8*)qp1,  q11 = *(const bf16x8*)(qp1 + 32);

    f32x4 o0[4], o1[4];
    float m0 = -__builtin_inff(), m1 = -__builtin_inff(), l0 = 0.f, l1 = 0.f;
#pragma unroll
    for (int t = 0; t < 4; t++) { o0[t] = (f32x4){0,0,0,0}; o1[t] = (f32x4){0,0,0,0}; }

    for (int kt = c * 16 + wg; kt <= tend; kt += 4) {
        const short* kb = Kb + bbase + (size_t)kt * 64 * 64;
        f32x4 s0[4], s1[4];
#pragma unroll
        for (int cc = 0; cc < 4; cc++) {
            const short* kp = kb + (size_t)(cc * 16 + l15) * 64 + h * 8;
            const bf16x8 kf0 = *(const bf16x8*)kp;
            const bf16x8 kf1 = *(const bf16x8*)(kp + 32);
            f32x4 z = (f32x4){0,0,0,0};
            z = MFMA32(kf0, q00, z);  s0[cc] = MFMA32(kf1, q01, z);
            z = (f32x4){0,0,0,0};
            z = MFMA32(kf0, q10, z);  s1[cc] = MFMA32(kf1, q11, z);
        }
        if (kt == lt) {   // diagonal: mask key > q
            const int q0g = row32 + l15, q1g = q0g + 16;
#pragma unroll
            for (int cc = 0; cc < 4; cc++) {
#pragma unroll
                for (int r = 0; r < 4; r++) {
                    const int key = kt * 64 + cc * 16 + h * 4 + r;
                    if (key > q0g) s0[cc][r] = -1e30f;
                    if (key > q1g) s1[cc][r] = -1e30f;
                }
            }
        }
        bf16x4 pb0[4], pb1[4];
        softmax_update(s0, m0, l0, o0, pb0);
        softmax_update(s1, m1, l1, o1, pb1);

        const short* vb = Vt + (size_t)b * 64 * 4096 + kt * 64;
#pragma unroll
        for (int ct = 0; ct < 4; ct++) {
            const short* vp = vb + (size_t)(ct * 16 + l15) * 4096 + h * 4;
#pragma unroll
            for (int cc = 0; cc < 4; cc++) {
                const bf16x4 vf = *(const bf16x4*)(vp + cc * 16);
                o0[ct] = MFMA16(vf, pb0[cc], o0[ct]);
                o1[ct] = MFMA16(vf, pb1[cc], o1[ct]);
            }
        }
    }

    // ---- intra-block merge of the 4 wave partials ----
    __shared__ float c_m[4][32], c_l[4][32];
    __shared__ short c_ob[4][32][72];     // bf16, pad 72
    if (h == 0) {
        c_m[wg][l15] = m0;  c_m[wg][16 + l15] = m1;
        c_l[wg][l15] = l0;  c_l[wg][16 + l15] = l1;
    }
#pragma unroll
    for (int ct = 0; ct < 4; ct++) {
        *(uint32_t*)&c_ob[wg][l15][ct * 16 + h * 4]          = cvt_pk_bf16(o0[ct][0], o0[ct][1]);
        *(uint32_t*)&c_ob[wg][l15][ct * 16 + h * 4 + 2]      = cvt_pk_bf16(o0[ct][2], o0[ct][3]);
        *(uint32_t*)&c_ob[wg][16 + l15][ct * 16 + h * 4]     = cvt_pk_bf16(o1[ct][0], o1[ct][1]);
        *(uint32_t*)&c_ob[wg][16 + l15][ct * 16 + h * 4 + 2] = cvt_pk_bf16(o1[ct][2], o1[ct][3]);
    }
    __syncthreads();

    const int e = threadIdx.x;
    const int q = e >> 3, d0 = (e & 7) * 8;
    float M = fmaxf(fmaxf(c_m[0][q], c_m[1][q]), fmaxf(c_m[2][q], c_m[3][q]));
    float L = 0.f;
    float acc[8];
#pragma unroll
    for (int i = 0; i < 8; i++) acc[i] = 0.f;
#pragma unroll
    for (int ww = 0; ww < 4; ww++) {
        const float ew = exp2f(c_m[ww][q] - M);
        L += ew * c_l[ww][q];
        const bf16x8 ov = *(const bf16x8*)&c_ob[ww][q][d0];
#pragma unroll
        for (int i = 0; i < 8; i++) acc[i] += ew * bf2f(ov[i]);
    }
    if ((e & 7) == 0) { PM[(size_t)j * 32 + q] = M; PL[(size_t)j * 32 + q] = L; }
    uint4 pk;
    pk.x = cvt_pk_bf16(acc[0], acc[1]);
    pk.y = cvt_pk_bf16(acc[2], acc[3]);
    pk.z = cvt_pk_bf16(acc[4], acc[5]);
    pk.w = cvt_pk_bf16(acc[6], acc[7]);
    *(uint4*)(PO + (size_t)j * 2048 + q * 64 + d0) = pk;
}

// ---------------------------------------------------------------------------
// Kernel 4: merge <=4 chunk partials per (b, qtile) and write output.
// ---------------------------------------------------------------------------
__global__ __launch_bounds__(256) void attn_merge(
        const short* __restrict__ PO, const float* __restrict__ PM,
        const float* __restrict__ PL, float* __restrict__ out) {
    const int bu = blockIdx.x;
    const int b = bu >> 7, u = bu & 127;
    const int off = (u < 32) ? u
                 : (u < 64) ? 32 + 2 * (u - 32)
                 : (u < 96) ? 96 + 3 * (u - 64)
                 :            192 + 4 * (u - 96);
    const int nc = (u + 32) >> 5;          // ceil((u+1)/32)
    const int base = b * 320 + off;
    const int e = threadIdx.x;
    const int q = e >> 3, d0 = (e & 7) * 8;

    float M = -__builtin_inff();
    for (int c = 0; c < nc; c++) M = fmaxf(M, PM[(size_t)(base + c) * 32 + q]);
    float L = 0.f;
    float acc[8];
#pragma unroll
    for (int i = 0; i < 8; i++) acc[i] = 0.f;
    for (int c = 0; c < nc; c++) {
        const size_t slot = base + c;
        const float ew = exp2f(PM[slot * 32 + q] - M);
        L += ew * PL[slot * 32 + q];
        const bf16x8 ov = *(const bf16x8*)(PO + slot * 2048 + q * 64 + d0);
#pragma unroll
        for (int i = 0; i < 8; i++) acc[i] += ew * bf2f(ov[i]);
    }
    const float inv = 1.0f / L;
    float4 w0, w1;
    w0.x = acc[0] * inv; w0.y = acc[1] * inv; w0.z = acc[2] * inv; w0.w = acc[3] * inv;
    w1.x = acc[4] * inv; w1.y = acc[5] * inv; w1.z = acc[6] * inv; w1.w = acc[7] * inv;
    float* dst = out + (size_t)b * 4096 * 64 + (size_t)(u * 32 + q) * 64 + d0;
    *(float4*)dst = w0;
    *(float4*)(dst + 4) = w1;
}

// ---------------------------------------------------------------------------
extern "C" void kernel_launch(void* const* d_in, const int* in_sizes, int n_in,
                              void* d_out, int out_size, void* d_ws, size_t ws_size,
                              hipStream_t stream) {
    const float* x  = (const float*)d_in[0];
    // d_in[1] = causal mask (structure known, not read)
    const float* Wk = (const float*)d_in[2];
    const float* bk = (const float*)d_in[3];
    const float* Wq = (const float*)d_in[4];
    const float* bq = (const float*)d_in[5];
    const float* Wv = (const float*)d_in[6];
    const float* bv = (const float*)d_in[7];
    float* out = (float*)d_out;

    char* ws = (char*)d_ws;
    short* WT    = (short*)(ws);                          // 384 KB
    float* biasC = (float*)(ws + 393216);                 // 768 B
    short* Qb    = (short*)(ws + (size_t)1  * (1 << 20)); // 2 MB (exp2-scaled)
    short* Kb    = (short*)(ws + (size_t)3  * (1 << 20)); // 2 MB
    short* Vt    = (short*)(ws + (size_t)5  * (1 << 20)); // 2 MB, [b][hd][s]
    short* PO    = (short*)(ws + (size_t)7  * (1 << 20)); // 1280*4KB = 5.25 MB
    float* PM    = (float*)(ws + (size_t)13 * (1 << 20)); // 160 KB
    float* PL    = (float*)(ws + (size_t)14 * (1 << 20)); // 160 KB

    wt_prep<<<768, 256, 0, stream>>>(Wk, bk, Wq, bq, Wv, bv, WT, biasC);
    qkv_proj<<<1024, 256, 0, stream>>>(x, WT, biasC, Qb, Kb, Vt);
    attn<<<1280, 256, 0, stream>>>(Qb, Kb, Vt, PO, PM, PL);
    attn_merge<<<512, 256, 0, stream>>>(PO, PM, PL, out);
}